// Round 8
// baseline (137.722 us; speedup 1.0000x reference)
//
#include <hip/hip_runtime.h>

// WassersteinLoss: out = scale * sum_{b,c,t} |a-b| * (T - t)
// R7: last ablation on the dual-path streamer. (1) DMA path now nt (aux=2)
// to skip L1 allocation — tests whether the shared dual-path limiter is the
// L1 fill port. (2) Both iterations' loads issued up-front (16 instrs,
// 16 KB/wave in flight), partial vmcnt(8) wait before consuming seg0 so
// 8 KB/wave stays in flight during consumption.
// 2048 blocks x 256 thr; 32 KB LDS; no workgroup barrier in the stream.

#define T_MASK 8191
#define T_DIMF 8192.0f

#define FLOATS_PER_BLOCK 8192      // per array
#define WAVE_CHUNK 1024            // floats per wave per segment (4 KB)

// s_waitcnt imm: vmcnt[3:0]|[15:14], expcnt[6:4], lgkmcnt[11:8]
#define WAITCNT_VM8 0x0F78         // vmcnt<=8, lgkm/exp don't-wait
#define WAITCNT_VM0 0x0F70         // vmcnt<=0, lgkm/exp don't-wait

typedef float vfloat4 __attribute__((ext_vector_type(4)));

__device__ __forceinline__ void load_lds16_nt(const float* g, float* l) {
    __builtin_amdgcn_global_load_lds(
        (const __attribute__((address_space(1))) void*)g,
        (__attribute__((address_space(3))) void*)l,
        16 /*bytes per lane*/, 0 /*offset*/, 2 /*aux: nt*/);
}

__global__ __launch_bounds__(256)
void wl_partial_kernel(const float* __restrict__ a,
                       const float* __restrict__ b,
                       float* __restrict__ partial) {
    // [segment][wave][floats] — each buffer written+read exactly once
    __shared__ float ldsB[2][4][WAVE_CHUNK];   // 32 KB

    const int tid  = threadIdx.x;
    const int lane = tid & 63;
    const int wave = tid >> 6;                 // 0..3
    const int blockBase = blockIdx.x * FLOATS_PER_BLOCK;

    const int seg0 = blockBase + wave * WAVE_CHUNK;                    // it 0
    const int seg1 = blockBase + 4 * WAVE_CHUNK + wave * WAVE_CHUNK;   // it 1
    float* l0 = &ldsB[0][wave][0];
    float* l1 = &ldsB[1][wave][0];
    const vfloat4* a4 = (const vfloat4*)a;
    const int b40 = seg0 >> 2;
    const int b41 = seg1 >> 2;

    // ---- issue ALL loads up-front (vmcnt FIFO order matters) ----
    // 1-4: DMA seg0 of b (nt)
    #pragma unroll
    for (int s = 0; s < 4; ++s)
        load_lds16_nt(b + seg0 + s * 256 + lane * 4, l0 + s * 256);
    // 5-8: vector seg0 of a (nt)
    vfloat4 xa0[4];
    #pragma unroll
    for (int s = 0; s < 4; ++s)
        xa0[s] = __builtin_nontemporal_load(&a4[b40 + s * 64 + lane]);
    // 9-12: DMA seg1 of b (nt)
    #pragma unroll
    for (int s = 0; s < 4; ++s)
        load_lds16_nt(b + seg1 + s * 256 + lane * 4, l1 + s * 256);
    // 13-16: vector seg1 of a (nt)
    vfloat4 xa1[4];
    #pragma unroll
    for (int s = 0; s < 4; ++s)
        xa1[s] = __builtin_nontemporal_load(&a4[b41 + s * 64 + lane]);

    float acc = 0.0f;

    // ---- consume seg0 while seg1's 8 loads remain in flight ----
    __builtin_amdgcn_s_waitcnt(WAITCNT_VM8);   // first 8 (seg0 DMA+vec) done
    __asm__ __volatile__("" ::: "memory");
    #pragma unroll
    for (int s = 0; s < 4; ++s) {
        vfloat4 y = ((const vfloat4*)l0)[s * 64 + lane];
        const int g = (b40 + s * 64 + lane) * 4;     // global float idx of .x
        float w = T_DIMF - (float)(g & T_MASK);      // 4|T: no row wrap
        float d0 = fabsf(xa0[s].x - y.x);
        float d1 = fabsf(xa0[s].y - y.y);
        float d2 = fabsf(xa0[s].z - y.z);
        float d3 = fabsf(xa0[s].w - y.w);
        acc += w * (d0 + d1 + d2 + d3) - (d1 + 2.0f * d2 + 3.0f * d3);
    }

    // ---- consume seg1 ----
    __builtin_amdgcn_s_waitcnt(WAITCNT_VM0);
    __asm__ __volatile__("" ::: "memory");
    #pragma unroll
    for (int s = 0; s < 4; ++s) {
        vfloat4 y = ((const vfloat4*)l1)[s * 64 + lane];
        const int g = (b41 + s * 64 + lane) * 4;
        float w = T_DIMF - (float)(g & T_MASK);
        float d0 = fabsf(xa1[s].x - y.x);
        float d1 = fabsf(xa1[s].y - y.y);
        float d2 = fabsf(xa1[s].z - y.z);
        float d3 = fabsf(xa1[s].w - y.w);
        acc += w * (d0 + d1 + d2 + d3) - (d1 + 2.0f * d2 + 3.0f * d3);
    }

    // wave-64 shuffle reduction
    #pragma unroll
    for (int off = 32; off > 0; off >>= 1)
        acc += __shfl_down(acc, off, 64);

    __shared__ float wave_sums[4];
    if (lane == 0) wave_sums[wave] = acc;
    __syncthreads();

    if (tid == 0)
        partial[blockIdx.x] = wave_sums[0] + wave_sums[1] + wave_sums[2] + wave_sums[3];
}

__global__ __launch_bounds__(256)
void wl_final_kernel(const float* __restrict__ partial, int n,
                     float* __restrict__ out, float scale) {
    float acc = 0.0f;
    for (int i = threadIdx.x; i < n; i += 256)
        acc += partial[i];

    #pragma unroll
    for (int off = 32; off > 0; off >>= 1)
        acc += __shfl_down(acc, off, 64);

    __shared__ float wave_sums[4];
    int lane = threadIdx.x & 63;
    int wave = threadIdx.x >> 6;
    if (lane == 0) wave_sums[wave] = acc;
    __syncthreads();

    if (threadIdx.x == 0)
        out[0] = (wave_sums[0] + wave_sums[1] + wave_sums[2] + wave_sums[3]) * scale;
}

extern "C" void kernel_launch(void* const* d_in, const int* in_sizes, int n_in,
                              void* d_out, int out_size, void* d_ws, size_t ws_size,
                              hipStream_t stream) {
    const float* a = (const float*)d_in[0];
    const float* b = (const float*)d_in[1];
    float* out = (float*)d_out;
    float* partial = (float*)d_ws;   // 2048 floats = 8 KB scratch

    int n = in_sizes[0];                     // 16,777,216
    int blocks = n / FLOATS_PER_BLOCK;       // 2048

    const long long T = 8192;
    const long long C = 64;
    const long long B = (long long)n / (C * T);
    float scale = (float)(2.0 / ((double)T * (double)C * (double)(T + 1) * (double)B));

    wl_partial_kernel<<<blocks, 256, 0, stream>>>(a, b, partial);
    wl_final_kernel<<<1, 256, 0, stream>>>(partial, blocks, out, scale);
}

// Round 9
// 130.244 us; speedup vs baseline: 1.0574x; 1.0574x over previous
//
#include <hip/hip_runtime.h>

// WassersteinLoss: out = scale * sum_{b,c,t} |a-b| * (T - t)
// FINAL (revert to R5, the measured best): dual-path streaming reader.
// Measured facts (R1-R7 on this MI355X):
//  - any single read mechanism (vector x4/x1, nt, global_load_lds) caps at
//    ~5.4 B/cyc/CU (~3.3 TB/s chip), latency-insensitive (L3-warm == HBM).
//  - vector-MSHR pool and LDS-DMA queue are SEPARATE pools: driving both
//    concurrently reaches ~8 B/cyc/CU (~4.9 TB/s), kernel ~27us for 134 MB.
//  - barrier-free wave-local drains (R6) and nt-DMA + partial-vmcnt
//    pipelining (R7) do NOT beat this: the combined rate is a shared
//    downstream return-port cap, not a software-structure artifact.
// a read via nt vector loads; b read via global_load_lds DMA; both in
// flight before one __syncthreads drain. 2048 blocks x 256 thr, 16 KB LDS.

#define T_MASK 8191
#define T_DIMF 8192.0f

#define FLOATS_PER_BLOCK 8192
#define CHUNK_FLOATS 4096          // 16 KB LDS chunk of b per iteration
#define NITER (FLOATS_PER_BLOCK / CHUNK_FLOATS)   // 2

typedef float vfloat4 __attribute__((ext_vector_type(4)));

__device__ __forceinline__ void load_lds16(const float* g, float* l) {
    __builtin_amdgcn_global_load_lds(
        (const __attribute__((address_space(1))) void*)g,
        (__attribute__((address_space(3))) void*)l,
        16 /*bytes per lane*/, 0 /*offset*/, 0 /*aux*/);
}

__global__ __launch_bounds__(256)
void wl_partial_kernel(const float* __restrict__ a,
                       const float* __restrict__ b,
                       float* __restrict__ partial) {
    __shared__ float ldsB[CHUNK_FLOATS];

    const int tid  = threadIdx.x;
    const int lane = tid & 63;
    const int wave = tid >> 6;                   // 0..3
    const int blockBase = blockIdx.x * FLOATS_PER_BLOCK;

    float acc = 0.0f;

    for (int it = 0; it < NITER; ++it) {
        const int chunkBase = blockBase + it * CHUNK_FLOATS;

        // Path 1: DMA b-chunk into LDS (4 instrs/wave, 4 KB/wave in flight).
        // LDS dest is wave-uniform base; HW scatters lane i at base+16*i.
        #pragma unroll
        for (int s = 0; s < 4; ++s) {
            const int seg = wave * 1024 + s * 256;       // float offset (uniform)
            load_lds16(b + chunkBase + seg + lane * 4, &ldsB[seg]);
        }

        // Path 2: nt vector loads of the matching a-chunk into VGPRs
        // (4 instrs/thread, issued while the DMA is still in flight).
        vfloat4 xa[4];
        const vfloat4* a4 = (const vfloat4*)a;
        const int c4 = chunkBase >> 2;                   // float4 base of chunk
        #pragma unroll
        for (int k = 0; k < 4; ++k)
            xa[k] = __builtin_nontemporal_load(&a4[c4 + tid + k * 256]);

        __syncthreads();   // vmcnt(0) drain: both paths complete

        #pragma unroll
        for (int k = 0; k < 4; ++k) {
            const int f4 = tid + k * 256;                // float4 index in chunk
            vfloat4 y = ((const vfloat4*)ldsB)[f4];
            const int g = chunkBase + f4 * 4;            // global float idx of .x
            float w = T_DIMF - (float)(g & T_MASK);      // 4|T so no row wrap
            float d0 = fabsf(xa[k].x - y.x);
            float d1 = fabsf(xa[k].y - y.y);
            float d2 = fabsf(xa[k].z - y.z);
            float d3 = fabsf(xa[k].w - y.w);
            acc += w * (d0 + d1 + d2 + d3) - (d1 + 2.0f * d2 + 3.0f * d3);
        }
        __syncthreads();   // protect ldsB before next iteration's DMA
    }

    // wave-64 shuffle reduction
    #pragma unroll
    for (int off = 32; off > 0; off >>= 1)
        acc += __shfl_down(acc, off, 64);

    __shared__ float wave_sums[4];
    if (lane == 0) wave_sums[wave] = acc;
    __syncthreads();

    if (tid == 0)
        partial[blockIdx.x] = wave_sums[0] + wave_sums[1] + wave_sums[2] + wave_sums[3];
}

__global__ __launch_bounds__(256)
void wl_final_kernel(const float* __restrict__ partial, int n,
                     float* __restrict__ out, float scale) {
    float acc = 0.0f;
    for (int i = threadIdx.x; i < n; i += 256)
        acc += partial[i];

    #pragma unroll
    for (int off = 32; off > 0; off >>= 1)
        acc += __shfl_down(acc, off, 64);

    __shared__ float wave_sums[4];
    int lane = threadIdx.x & 63;
    int wave = threadIdx.x >> 6;
    if (lane == 0) wave_sums[wave] = acc;
    __syncthreads();

    if (threadIdx.x == 0)
        out[0] = (wave_sums[0] + wave_sums[1] + wave_sums[2] + wave_sums[3]) * scale;
}

extern "C" void kernel_launch(void* const* d_in, const int* in_sizes, int n_in,
                              void* d_out, int out_size, void* d_ws, size_t ws_size,
                              hipStream_t stream) {
    const float* a = (const float*)d_in[0];
    const float* b = (const float*)d_in[1];
    float* out = (float*)d_out;
    float* partial = (float*)d_ws;   // 2048 floats = 8 KB scratch

    int n = in_sizes[0];                     // 16,777,216
    int blocks = n / FLOATS_PER_BLOCK;       // 2048

    const long long T = 8192;
    const long long C = 64;
    const long long B = (long long)n / (C * T);
    float scale = (float)(2.0 / ((double)T * (double)C * (double)(T + 1) * (double)B));

    wl_partial_kernel<<<blocks, 256, 0, stream>>>(a, b, partial);
    wl_final_kernel<<<1, 256, 0, stream>>>(partial, blocks, out, scale);
}